// Round 13
// baseline (52.250 us; speedup 1.0000x reference)
//
#include <hip/hip_runtime.h>
#include <cstdint>
#include <cstddef>

// HyperNetwork, single fused kernel (EXACT R10 best structure; only change:
// phase-1a unroll 8 -> 32 to cut the serial W_in load chain 8 rounds -> 2):
//   Out[b,c,f] = sum_n X[b,c,n] * W_eff[c,f,n] + b_eff[c,f]
//   W_eff[c] = W_out(9x64) @ W_in[c](64x256); b_eff = W_out@b_in[c] + b_out.
//
// One block per channel c (512 blocks, 512 thr = 8 waves):
//   Phase 0:  prefetch tile s=0 into regs (16 dwordx4 in flight under phase 1,
//             pinned by keep-alive asm before the barrier).
//   Phase 1a: W_eff[c] -> w_lds, threads 0..255, unroll 32 (32 loads in flight).
//   Phase 1b: RTNE hi/lo bf16 fragment emit -> LDS.
//   Phase 1c: per-lane fragment load.
//   Phase 2:  s=0 consumes prefetched xv, s=1 loads inline; 3-term bf16 MFMA.

#define CC 512
#define NZ 256
#define ZD 64
#define NF 9

typedef __attribute__((ext_vector_type(4))) float f32x4;
typedef __attribute__((ext_vector_type(8))) short bf16x8;
typedef __attribute__((ext_vector_type(4))) unsigned int u32x4;

__device__ __forceinline__ unsigned short f2bf(float f) {   // RTNE
  unsigned int u = __builtin_bit_cast(unsigned int, f);
  unsigned int r = (u + 0x7fffu + ((u >> 16) & 1u)) >> 16;
  return (unsigned short)r;
}
__device__ __forceinline__ float bf2f(unsigned short u) {
  unsigned int x = ((unsigned int)u) << 16;
  return __builtin_bit_cast(float, x);
}

// split 8 f32 -> bf16 hi (trunc) + bf16 lo (residual) — EXACT verified split8
__device__ __forceinline__ void split8(f32x4 x0, f32x4 x1,
                                       bf16x8* xh, bf16x8* xl) {
  unsigned u[8], r[8];
#pragma unroll
  for (int j = 0; j < 4; ++j) {
    u[j]     = __builtin_bit_cast(unsigned, x0[j]);
    u[4 + j] = __builtin_bit_cast(unsigned, x1[j]);
  }
#pragma unroll
  for (int j = 0; j < 8; ++j) {
    float hf = __builtin_bit_cast(float, u[j] & 0xffff0000u);
    float xf = (j < 4) ? x0[j] : x1[j - 4];
    r[j] = __builtin_bit_cast(unsigned, xf - hf);
  }
  u32x4 h, l;
#pragma unroll
  for (int d = 0; d < 4; ++d) {
    h[d] = __builtin_amdgcn_perm(u[2 * d + 1], u[2 * d], 0x07060302u);
    l[d] = __builtin_amdgcn_perm(r[2 * d + 1], r[2 * d], 0x07060302u);
  }
  *xh = __builtin_bit_cast(bf16x8, h);
  *xl = __builtin_bit_cast(bf16x8, l);
}

__global__ __launch_bounds__(512, 4)
void hyper_one(const float* __restrict__ z,
               const float* __restrict__ W_in,
               const float* __restrict__ b_in,
               const float* __restrict__ W_out,
               const float* __restrict__ b_out,
               float* __restrict__ out)
{
  __shared__ float w_lds[NF * NZ];                        // 9216 B
  __shared__ float b_lds[16];
  __shared__ __align__(16) unsigned short fh[8 * 64 * 8]; // 8 KB [ks][l][j]
  __shared__ __align__(16) unsigned short fl[8 * 64 * 8]; // 8 KB

  const int c = blockIdx.x;
  const int t = threadIdx.x;
  const int lane = t & 63;
  const int w = t >> 6;          // 0..7
  const int g = lane >> 4;
  const int l4 = lane & 15;

  // ---------- Phase 0: prefetch tile s=0 (EXACT R10) ----------
  const float* xr0 = z + ((size_t)(w * 32 + l4) * CC + c) * NZ + g * 8;
  f32x4 xv[16];
#pragma unroll
  for (int ks = 0; ks < 8; ++ks) {
    xv[2 * ks]     = *(const f32x4*)(xr0 + ks * 32);
    xv[2 * ks + 1] = *(const f32x4*)(xr0 + ks * 32 + 4);
  }

  // ---------- Phase 1a: W_eff[f][n] (R10, unroll 8 -> 32) ----------
  if (t < NZ) {
    float acc[NF];
#pragma unroll
    for (int f = 0; f < NF; ++f) acc[f] = 0.f;
    const float* wi = W_in + (size_t)c * ZD * NZ + t;
#pragma unroll 32
    for (int zz = 0; zz < ZD; ++zz) {
      float v = wi[(size_t)zz * NZ];              // 1KB coalesced per iter
#pragma unroll
      for (int f = 0; f < NF; ++f) acc[f] += W_out[f * ZD + zz] * v;  // s_load
    }
#pragma unroll
    for (int f = 0; f < NF; ++f) w_lds[f * NZ + t] = acc[f];
  }
  if (t < 16) {
    float bacc = 0.f;
    if (t < NF) {
      bacc = b_out[t];
      for (int zz = 0; zz < ZD; ++zz)
        bacc += b_in[(size_t)c * ZD + zz] * W_out[t * ZD + zz];
    }
    b_lds[t] = bacc;
  }
  __syncthreads();

  // ---------- Phase 1b: fragment emit (EXACT R10) ----------
  {
    const int u = t;
    const int ks = u >> 6, l = u & 63;
    const int f = l & 15, g2 = l >> 4;
    bf16x8 hv, lv;
#pragma unroll
    for (int j = 0; j < 8; ++j) {
      float v = (f < NF) ? w_lds[f * NZ + ks * 32 + g2 * 8 + j] : 0.f;
      unsigned short hh = f2bf(v);
      hv[j] = (short)hh;
      lv[j] = (short)f2bf(v - bf2f(hh));
    }
    *(bf16x8*)&fh[(ks * 64 + l) * 8] = hv;
    *(bf16x8*)&fl[(ks * 64 + l) * 8] = lv;
  }

  // pin the prefetched tile live here (loads must not sink past the barrier)
#pragma unroll
  for (int k = 0; k < 16; ++k)
    asm volatile("" : "+v"(xv[k]));

  __syncthreads();

  // ---------- Phase 1c: per-lane fragment load (EXACT R10) ----------
  bf16x8 wh[8], wl[8];
#pragma unroll
  for (int ks = 0; ks < 8; ++ks) {
    wh[ks] = *(const bf16x8*)&fh[(ks * 64 + lane) * 8];
    wl[ks] = *(const bf16x8*)&fl[(ks * 64 + lane) * 8];
  }
  const f32x4 bv = {b_lds[g * 4 + 0], b_lds[g * 4 + 1],
                    b_lds[g * 4 + 2], b_lds[g * 4 + 3]};

  // ---------- Phase 2: EXACT R10 loop; s=0 from xv, s=1 loads --------
#pragma unroll
  for (int s = 0; s < 2; ++s) {
    const int b = w * 32 + s * 16 + l4;
    const float* xr = z + ((size_t)b * CC + c) * NZ + g * 8;

    f32x4 acc = {0.f, 0.f, 0.f, 0.f};
#pragma unroll
    for (int ks = 0; ks < 8; ++ks) {
      f32x4 x0, x1;
      if (s == 0) {
        x0 = xv[2 * ks];
        x1 = xv[2 * ks + 1];
      } else {
        x0 = *(const f32x4*)(xr + ks * 32);
        x1 = *(const f32x4*)(xr + ks * 32 + 4);
      }
      bf16x8 xh, xl;
      split8(x0, x1, &xh, &xl);
      acc = __builtin_amdgcn_mfma_f32_16x16x32_bf16(wh[ks], xh, acc, 0, 0, 0);
      acc = __builtin_amdgcn_mfma_f32_16x16x32_bf16(wl[ks], xh, acc, 0, 0, 0);
      acc = __builtin_amdgcn_mfma_f32_16x16x32_bf16(wh[ks], xl, acc, 0, 0, 0);
    }

    // D[row=f=g*4+reg][col=b=l4] (verified C/D map)
    float* ob = out + ((size_t)b * CC + c) * NF;
    if (g < 2) {
#pragma unroll
      for (int reg = 0; reg < 4; ++reg)
        ob[g * 4 + reg] = acc[reg] + bv[reg];
    } else if (g == 2) {
      ob[8] = acc[0] + bv[0];
    }
  }
}

extern "C" void kernel_launch(void* const* d_in, const int* in_sizes, int n_in,
                              void* d_out, int out_size, void* d_ws, size_t ws_size,
                              hipStream_t stream) {
  const float* z     = (const float*)d_in[0];
  const float* W_in  = (const float*)d_in[1];
  const float* b_in  = (const float*)d_in[2];
  const float* W_out = (const float*)d_in[3];
  const float* b_out = (const float*)d_in[4];
  float* out = (float*)d_out;

  hipLaunchKernelGGL(hyper_one, dim3(CC), dim3(512), 0, stream,
                     z, W_in, b_in, W_out, b_out, out);
}

// Round 14
// 33.589 us; speedup vs baseline: 1.5556x; 1.5556x over previous
//
#include <hip/hip_runtime.h>
#include <cstdint>
#include <cstddef>

// HyperNetwork, single fused kernel (EXACT R10 structure; one change: wh/wl
// fragments are loaded TRANSIENTLY inside the phase-2 loop instead of being
// held in 64 VGPRs for the whole kernel — frees the register budget so the
// phase-0 z-prefetch xv[16] can actually stay register-resident instead of
// spilling to scratch; R12/R13 profiles showed VGPR_Count=52-64, impossible
// with xv+wh/wl live => spill was eating the prefetch's benefit):
//   Out[b,c,f] = sum_n X[b,c,n] * W_eff[c,f,n] + b_eff[c,f]
//   W_eff[c] = W_out(9x64) @ W_in[c](64x256); b_eff = W_out@b_in[c] + b_out.

#define CC 512
#define NZ 256
#define ZD 64
#define NF 9

typedef __attribute__((ext_vector_type(4))) float f32x4;
typedef __attribute__((ext_vector_type(8))) short bf16x8;
typedef __attribute__((ext_vector_type(4))) unsigned int u32x4;

__device__ __forceinline__ unsigned short f2bf(float f) {   // RTNE
  unsigned int u = __builtin_bit_cast(unsigned int, f);
  unsigned int r = (u + 0x7fffu + ((u >> 16) & 1u)) >> 16;
  return (unsigned short)r;
}
__device__ __forceinline__ float bf2f(unsigned short u) {
  unsigned int x = ((unsigned int)u) << 16;
  return __builtin_bit_cast(float, x);
}

// split 8 f32 -> bf16 hi (trunc) + bf16 lo (residual) — EXACT verified split8
__device__ __forceinline__ void split8(f32x4 x0, f32x4 x1,
                                       bf16x8* xh, bf16x8* xl) {
  unsigned u[8], r[8];
#pragma unroll
  for (int j = 0; j < 4; ++j) {
    u[j]     = __builtin_bit_cast(unsigned, x0[j]);
    u[4 + j] = __builtin_bit_cast(unsigned, x1[j]);
  }
#pragma unroll
  for (int j = 0; j < 8; ++j) {
    float hf = __builtin_bit_cast(float, u[j] & 0xffff0000u);
    float xf = (j < 4) ? x0[j] : x1[j - 4];
    r[j] = __builtin_bit_cast(unsigned, xf - hf);
  }
  u32x4 h, l;
#pragma unroll
  for (int d = 0; d < 4; ++d) {
    h[d] = __builtin_amdgcn_perm(u[2 * d + 1], u[2 * d], 0x07060302u);
    l[d] = __builtin_amdgcn_perm(r[2 * d + 1], r[2 * d], 0x07060302u);
  }
  *xh = __builtin_bit_cast(bf16x8, h);
  *xl = __builtin_bit_cast(bf16x8, l);
}

__global__ __launch_bounds__(512, 4)
void hyper_one(const float* __restrict__ z,
               const float* __restrict__ W_in,
               const float* __restrict__ b_in,
               const float* __restrict__ W_out,
               const float* __restrict__ b_out,
               float* __restrict__ out)
{
  __shared__ float w_lds[NF * NZ];                        // 9216 B
  __shared__ float b_lds[16];
  __shared__ __align__(16) unsigned short fh[8 * 64 * 8]; // 8 KB [ks][l][j]
  __shared__ __align__(16) unsigned short fl[8 * 64 * 8]; // 8 KB

  const int c = blockIdx.x;
  const int t = threadIdx.x;
  const int lane = t & 63;
  const int w = t >> 6;          // 0..7
  const int g = lane >> 4;
  const int l4 = lane & 15;

  // ---------- Phase 0: prefetch tile s=0 (EXACT R10) ----------
  const float* xr0 = z + ((size_t)(w * 32 + l4) * CC + c) * NZ + g * 8;
  f32x4 xv[16];
#pragma unroll
  for (int ks = 0; ks < 8; ++ks) {
    xv[2 * ks]     = *(const f32x4*)(xr0 + ks * 32);
    xv[2 * ks + 1] = *(const f32x4*)(xr0 + ks * 32 + 4);
  }

  // ---------- Phase 1a: W_eff[f][n] (EXACT R10, threads 0..255) ----------
  if (t < NZ) {
    float acc[NF];
#pragma unroll
    for (int f = 0; f < NF; ++f) acc[f] = 0.f;
    const float* wi = W_in + (size_t)c * ZD * NZ + t;
#pragma unroll 8
    for (int zz = 0; zz < ZD; ++zz) {
      float v = wi[(size_t)zz * NZ];              // 1KB coalesced per iter
#pragma unroll
      for (int f = 0; f < NF; ++f) acc[f] += W_out[f * ZD + zz] * v;  // s_load
    }
#pragma unroll
    for (int f = 0; f < NF; ++f) w_lds[f * NZ + t] = acc[f];
  }
  if (t < 16) {
    float bacc = 0.f;
    if (t < NF) {
      bacc = b_out[t];
      for (int zz = 0; zz < ZD; ++zz)
        bacc += b_in[(size_t)c * ZD + zz] * W_out[t * ZD + zz];
    }
    b_lds[t] = bacc;
  }
  __syncthreads();

  // ---------- Phase 1b: fragment emit (EXACT R10) ----------
  {
    const int u = t;
    const int ks = u >> 6, l = u & 63;
    const int f = l & 15, g2 = l >> 4;
    bf16x8 hv, lv;
#pragma unroll
    for (int j = 0; j < 8; ++j) {
      float v = (f < NF) ? w_lds[f * NZ + ks * 32 + g2 * 8 + j] : 0.f;
      unsigned short hh = f2bf(v);
      hv[j] = (short)hh;
      lv[j] = (short)f2bf(v - bf2f(hh));
    }
    *(bf16x8*)&fh[(ks * 64 + l) * 8] = hv;
    *(bf16x8*)&fl[(ks * 64 + l) * 8] = lv;
  }

  // pin the prefetched tile live here (loads must not sink past the barrier)
#pragma unroll
  for (int k = 0; k < 16; ++k)
    asm volatile("" : "+v"(xv[k]));

  __syncthreads();

  const f32x4 bv = {b_lds[g * 4 + 0], b_lds[g * 4 + 1],
                    b_lds[g * 4 + 2], b_lds[g * 4 + 3]};

  // ---------- Phase 2: R10 loop; wh/wl loaded TRANSIENTLY per ks ----------
#pragma unroll
  for (int s = 0; s < 2; ++s) {
    const int b = w * 32 + s * 16 + l4;
    const float* xr = z + ((size_t)b * CC + c) * NZ + g * 8;

    f32x4 acc = {0.f, 0.f, 0.f, 0.f};
#pragma unroll
    for (int ks = 0; ks < 8; ++ks) {
      const bf16x8 whk = *(const bf16x8*)&fh[(ks * 64 + lane) * 8];
      const bf16x8 wlk = *(const bf16x8*)&fl[(ks * 64 + lane) * 8];
      f32x4 x0, x1;
      if (s == 0) {
        x0 = xv[2 * ks];
        x1 = xv[2 * ks + 1];
      } else {
        x0 = *(const f32x4*)(xr + ks * 32);
        x1 = *(const f32x4*)(xr + ks * 32 + 4);
      }
      bf16x8 xh, xl;
      split8(x0, x1, &xh, &xl);
      acc = __builtin_amdgcn_mfma_f32_16x16x32_bf16(whk, xh, acc, 0, 0, 0);
      acc = __builtin_amdgcn_mfma_f32_16x16x32_bf16(wlk, xh, acc, 0, 0, 0);
      acc = __builtin_amdgcn_mfma_f32_16x16x32_bf16(whk, xl, acc, 0, 0, 0);
    }

    // D[row=f=g*4+reg][col=b=l4] (verified C/D map)
    float* ob = out + ((size_t)b * CC + c) * NF;
    if (g < 2) {
#pragma unroll
      for (int reg = 0; reg < 4; ++reg)
        ob[g * 4 + reg] = acc[reg] + bv[reg];
    } else if (g == 2) {
      ob[8] = acc[0] + bv[0];
    }
  }
}

extern "C" void kernel_launch(void* const* d_in, const int* in_sizes, int n_in,
                              void* d_out, int out_size, void* d_ws, size_t ws_size,
                              hipStream_t stream) {
  const float* z     = (const float*)d_in[0];
  const float* W_in  = (const float*)d_in[1];
  const float* b_in  = (const float*)d_in[2];
  const float* W_out = (const float*)d_in[3];
  const float* b_out = (const float*)d_in[4];
  float* out = (float*)d_out;

  hipLaunchKernelGGL(hyper_one, dim3(CC), dim3(512), 0, stream,
                     z, W_in, b_in, W_out, b_out, out);
}